// Round 1
// 377.227 us; speedup vs baseline: 1.0214x; 1.0214x over previous
//
#include <hip/hip_runtime.h>

#define BB 4
#define SS 4096
#define DD 64
#define QB 32    // queries per block (2 query-waves x 16)
#define TK 32    // keys per slot (split-K=4 across key-waves)
#define NS 4     // key slots staged per iteration (128 keys/iter)
#define SV 72    // Vhi/Vlo LDS row stride (halfs): 144B rows, 16B-aligned b128
#define SVT 40   // VTr LDS row stride (halfs): 80B rows, 16B-aligned b128
#define SP 72    // P LDS stride (halfs)

typedef _Float16 h16;
typedef h16 half4_t __attribute__((ext_vector_type(4)));
typedef h16 half8_t __attribute__((ext_vector_type(8)));
typedef float f32x4 __attribute__((ext_vector_type(4)));

// 512 threads = 8 waves = 2 qgroups x 4 key-quarters. LDS 75776 B -> 2 blocks/CU
// -> 16 waves/CU (vs 8 before): the occupancy doubling is the point of this rev.
struct __align__(16) LdsBufs {
    h16 Vhi[NS][TK * SV];    // 18432 B  V tile f16 hi, [key][d]
    h16 Vlo[NS][TK * SV];    // 18432 B  f16x2 residual
    h16 VTr[NS][DD * SVT];   // 20480 B  V transposed [d][key] (hi only, for P·V)
    h16 Pl[8][16 * SP];      // 18432 B  per-wave P tile [q][key]
};
static_assert(sizeof(LdsBufs) <= 80 * 1024, "need 2 blocks/CU");

struct StReg { f32x4 v[4]; };

// T14 async-stage split: issue global loads early (into regs) ...
__device__ __forceinline__ void stage_load(StReg& r, const float* Vb, int it, int t) {
    const int c16 = t & 15;        // 16B column
    const int rg  = t >> 4;        // 0..31 -> rows rg*4+i of the 128-key super-tile
    const f32x4* Vg = (const f32x4*)(Vb + ((size_t)it * (NS * TK) + rg * 4) * DD);
#pragma unroll
    for (int i = 0; i < 4; ++i) r.v[i] = Vg[i * 16 + c16];
}

// ... convert + LDS-write late (after the barrier), f32->f16 hi/lo split (Sterbenz).
__device__ __forceinline__ void stage_write(const StReg& r, LdsBufs& L, int t, bool with_vt) {
    const int c16 = t & 15;
    const int rg  = t >> 4;
    const int ts  = rg >> 3;         // slot 0..3
    const int r0  = (rg & 7) * 4;    // row within slot
    half4_t hh[4];
#pragma unroll
    for (int i = 0; i < 4; ++i) {
        f32x4 v = r.v[i];
        half4_t hi, lo;
#pragma unroll
        for (int j = 0; j < 4; ++j) {
            float x = v[j];
            h16 h = (h16)x;
            hi[j] = h;
            lo[j] = (h16)(x - (float)h);   // exact residual
        }
        hh[i] = hi;
        *(half4_t*)&L.Vhi[ts][(r0 + i) * SV + c16 * 4] = hi;
        *(half4_t*)&L.Vlo[ts][(r0 + i) * SV + c16 * 4] = lo;
    }
    if (with_vt) {
#pragma unroll
        for (int j = 0; j < 4; ++j) {
            half4_t col;
#pragma unroll
            for (int i = 0; i < 4; ++i) col[i] = hh[i][j];
            *(half4_t*)&L.VTr[ts][(c16 * 4 + j) * SVT + r0] = col;
        }
    }
}

// S^T = V * Q^T on one 32-key slot, f16x2-split (err ~2^-20): 12 MFMA per call.
__device__ __forceinline__ void scores(const LdsBufs& L, int kq, int qi, int quad,
                                       const half8_t* qhi, const half8_t* qlo,
                                       f32x4* sc) {
    sc[0] = (f32x4){0.f, 0.f, 0.f, 0.f};
    sc[1] = (f32x4){0.f, 0.f, 0.f, 0.f};
#pragma unroll
    for (int ks = 0; ks < 2; ++ks) {
#pragma unroll
        for (int mt = 0; mt < 2; ++mt) {
            half8_t ahi = *(const half8_t*)&L.Vhi[kq][(mt * 16 + qi) * SV + ks * 32 + quad * 8];
            half8_t alo = *(const half8_t*)&L.Vlo[kq][(mt * 16 + qi) * SV + ks * 32 + quad * 8];
            sc[mt] = __builtin_amdgcn_mfma_f32_16x16x32_f16(ahi, qhi[ks], sc[mt], 0, 0, 0);
            sc[mt] = __builtin_amdgcn_mfma_f32_16x16x32_f16(ahi, qlo[ks], sc[mt], 0, 0, 0);
            sc[mt] = __builtin_amdgcn_mfma_f32_16x16x32_f16(alo, qhi[ks], sc[mt], 0, 0, 0);
        }
    }
}

__global__ __launch_bounds__(512, 4) void attn_fused(const float* __restrict__ Q,
                                                     const float* __restrict__ V,
                                                     float* __restrict__ ctx,
                                                     float* __restrict__ attn) {
    __shared__ LdsBufs L;
    const int t     = threadIdx.x;
    const int w     = t >> 6;
    const int lane  = t & 63;
    const int qi    = lane & 15;   // query (C col) / A-row index
    const int quad  = lane >> 4;   // 0..3
    const int qgrp  = w & 1;       // query group
    const int kq    = w >> 1;      // key quarter 0..3 (split-K=4)
    const int b     = blockIdx.y;
    const int qb    = blockIdx.x * QB + qgrp * 16;

    const float* Vb   = V + (size_t)b * SS * DD;
    const float* Qrow = Q + ((size_t)b * SS + qb + qi) * DD;

    // Q fragments, f16x2: lane holds Q[qi][ks*32 + quad*8 + j]
    half8_t qhi[2], qlo[2];
#pragma unroll
    for (int ks = 0; ks < 2; ++ks) {
        f32x4 a = *(const f32x4*)(Qrow + ks * 32 + quad * 8);
        f32x4 c = *(const f32x4*)(Qrow + ks * 32 + quad * 8 + 4);
#pragma unroll
        for (int j = 0; j < 4; ++j) {
            float x = a[j];
            h16 h = (h16)x;
            qhi[ks][j] = h;
            qlo[ks][j] = (h16)(x - (float)h);
            float y = c[j];
            h16 g = (h16)y;
            qhi[ks][j + 4] = g;
            qlo[ks][j + 4] = (h16)(y - (float)g);
        }
    }

    float mrun = -1e30f, lrun = 0.f;
    f32x4 oc[4];
#pragma unroll
    for (int mt = 0; mt < 4; ++mt) oc[mt] = (f32x4){0.f, 0.f, 0.f, 0.f};

    const int NIT = SS / (NS * TK);   // 32
    StReg r;
    stage_load(r, Vb, 0, t);

    // ---------------- Phase 1: online softmax, ctx accumulate ----------------
    for (int it = 0; it < NIT; ++it) {
        __syncthreads();                  // prev tile fully consumed
        stage_write(r, L, t, true);
        __syncthreads();
        if (it + 1 < NIT) stage_load(r, Vb, it + 1, t);   // hide L2 latency under compute

        f32x4 sc[2];
        scores(L, kq, qi, quad, qhi, qlo, sc);

        float tmax = -1e30f;
#pragma unroll
        for (int mt = 0; mt < 2; ++mt)
#pragma unroll
            for (int r4 = 0; r4 < 4; ++r4) tmax = fmaxf(tmax, sc[mt][r4]);
        tmax = fmaxf(tmax, __shfl_xor(tmax, 16));
        tmax = fmaxf(tmax, __shfl_xor(tmax, 32));
        float mn    = fmaxf(mrun, tmax);
        float alpha = __expf(mrun - mn);
        float psum  = 0.f;
        half4_t pv[2];
#pragma unroll
        for (int mt = 0; mt < 2; ++mt)
#pragma unroll
            for (int r4 = 0; r4 < 4; ++r4) {
                float p = __expf(sc[mt][r4] - mn);
                psum += p;
                pv[mt][r4] = (h16)p;
            }
        psum += __shfl_xor(psum, 16);
        psum += __shfl_xor(psum, 32);
        lrun = lrun * alpha + psum;
        mrun = mn;
#pragma unroll
        for (int mt = 0; mt < 2; ++mt)
            *(half4_t*)&L.Pl[w][qi * SP + mt * 16 + quad * 4] = pv[mt];
#pragma unroll
        for (int mt = 0; mt < 4; ++mt) oc[mt] *= alpha;

        // O^T += V^T * P^T : A = VTr[d][key], B = Pl[q][key]; K = 32 keys -> 1 mfma/mt
        half8_t bp = *(const half8_t*)&L.Pl[w][qi * SP + quad * 8];
#pragma unroll
        for (int mt = 0; mt < 4; ++mt) {
            half8_t av = *(const half8_t*)&L.VTr[kq][(mt * 16 + qi) * SVT + quad * 8];
            oc[mt] = __builtin_amdgcn_mfma_f32_16x16x32_f16(av, bp, oc[mt], 0, 0, 0);
        }
    }

    // prefetch phase-2 tile 0 before the merge (pure reg traffic, no LDS hazard)
    stage_load(r, Vb, 0, t);

    // ---------------- Merge 4 split-K partners (fixed order: bitwise-identical) --
    __syncthreads();
    {
        float* buf  = (float*)&L;            // 8*64*18*4 = 36864 B = Vhi+Vlo region
        float* mine = buf + t * 18;
        mine[0] = mrun;
        mine[1] = lrun;
#pragma unroll
        for (int mt = 0; mt < 4; ++mt)
#pragma unroll
            for (int r4 = 0; r4 < 4; ++r4) mine[2 + mt * 4 + r4] = oc[mt][r4];
        __syncthreads();
        float mf = -1e30f;
#pragma unroll
        for (int k2 = 0; k2 < 4; ++k2)
            mf = fmaxf(mf, buf[((k2 * 2 + qgrp) * 64 + lane) * 18]);
        float lf = 0.f;
        f32x4 on[4];
#pragma unroll
        for (int mt = 0; mt < 4; ++mt) on[mt] = (f32x4){0.f, 0.f, 0.f, 0.f};
#pragma unroll
        for (int k2 = 0; k2 < 4; ++k2) {
            const float* po = buf + ((k2 * 2 + qgrp) * 64 + lane) * 18;
            float e = __expf(po[0] - mf);
            lf += po[1] * e;
#pragma unroll
            for (int mt = 0; mt < 4; ++mt)
#pragma unroll
                for (int r4 = 0; r4 < 4; ++r4) on[mt][r4] += po[2 + mt * 4 + r4] * e;
        }
        mrun = mf;
        lrun = lf;
#pragma unroll
        for (int mt = 0; mt < 4; ++mt) oc[mt] = on[mt];
    }

    const float invl = 1.f / lrun;

    // ctx write (key-quarter 0 waves): lane holds d = mt*16+quad*4+r for q = qi
    if (kq == 0) {
        float* crow = ctx + ((size_t)b * SS + qb + qi) * DD;
#pragma unroll
        for (int mt = 0; mt < 4; ++mt) {
            f32x4 cv;
#pragma unroll
            for (int r4 = 0; r4 < 4; ++r4) cv[r4] = oc[mt][r4] * invl;
            *(f32x4*)&crow[mt * 16 + quad * 4] = cv;
        }
    }

    // ---------------- Phase 2: recompute scores, write normalized weights ----
    const float moff = mrun + __logf(lrun);   // exp(s-m)/l == exp(s-moff)
    float* arow = attn + ((size_t)b * SS + qb + qi) * SS;
    for (int it = 0; it < NIT; ++it) {
        __syncthreads();
        stage_write(r, L, t, false);
        __syncthreads();
        if (it + 1 < NIT) stage_load(r, Vb, it + 1, t);

        f32x4 sc[2];
        scores(L, kq, qi, quad, qhi, qlo, sc);
        const int kbase = it * (NS * TK) + kq * TK;
#pragma unroll
        for (int mt = 0; mt < 2; ++mt) {
            f32x4 wv;
#pragma unroll
            for (int r4 = 0; r4 < 4; ++r4) wv[r4] = __expf(sc[mt][r4] - moff);
            *(f32x4*)&arow[kbase + mt * 16 + quad * 4] = wv;
        }
    }
}

extern "C" void kernel_launch(void* const* d_in, const int* in_sizes, int n_in,
                              void* d_out, int out_size, void* d_ws, size_t ws_size,
                              hipStream_t stream) {
    const float* Q = (const float*)d_in[0];
    const float* V = (const float*)d_in[1];
    float* ctx  = (float*)d_out;
    float* attn = (float*)d_out + (size_t)BB * SS * DD;
    attn_fused<<<dim3(SS / QB, BB), 512, 0, stream>>>(Q, V, ctx, attn);
}

// Round 2
// 371.779 us; speedup vs baseline: 1.0363x; 1.0147x over previous
//
#include <hip/hip_runtime.h>

#define BB 4
#define SS 4096
#define DD 64
#define QB 32    // queries per block (2 query-waves x 16)
#define TK 32    // keys per slot (split-K=4 across key-waves)
#define NS 4     // key slots per staged tile (128 keys/iter)
#define SV 72    // Vhi/Vlo LDS row stride (halfs): 144B rows, 16B-aligned b128
#define SVT 40   // VTr LDS row stride (halfs): 80B rows, 16B-aligned b128
#define SP 72    // P LDS stride (halfs)
#define NIT (SS / (NS * TK))   // 32 tiles per batch

typedef _Float16 h16;
typedef h16 half4_t __attribute__((ext_vector_type(4)));
typedef h16 half8_t __attribute__((ext_vector_type(8)));
typedef float f32x4 __attribute__((ext_vector_type(4)));

// Exact byte image of the staged LDS region. prep_v writes it once per launch;
// attn_fused memcpys it tile-by-tile with global_load_lds (no VALU, no regs).
struct __align__(16) VTile {
    h16 Vhi[NS][TK * SV];    // 18432 B  V f16 hi, [key][d]
    h16 Vlo[NS][TK * SV];    // 18432 B  f16x2 residual (Sterbenz-exact)
    h16 VTr[NS][DD * SVT];   // 20480 B  V^T hi, [d][key] (for P.V)
};                           // 57344 B = 7 * 8192; Vhi+Vlo prefix = 36864 = 4.5 * 8192

struct __align__(16) LdsBufs {
    VTile T;
    h16 Pl[8][16 * SP];      // 18432 B per-wave P tile [q][key]
};                           // 75776 B -> 2 blocks/CU -> 16 waves/CU
static_assert(sizeof(VTile) == 57344, "image size");
static_assert(sizeof(LdsBufs) <= 80 * 1024, "need 2 blocks/CU");

typedef __attribute__((address_space(3))) uint32_t lds_u32;
typedef const __attribute__((address_space(1))) uint32_t gl_u32;

// Linear async copy: thread t moves 16B chunks at (i*512 + t)*16. Per wave the
// LDS dest is first-lane base + lane*16 == the same linear address: layout-safe.
__device__ __forceinline__ void stage_tile(const char* g, char* l, int t,
                                           int nfull, bool tail_half) {
#pragma unroll
    for (int i = 0; i < nfull; ++i) {
        const int off = (i * 512 + t) * 16;
        __builtin_amdgcn_global_load_lds((gl_u32*)(g + off), (lds_u32*)(l + off), 16, 0, 0);
    }
    if (tail_half && t < 256) {   // wave-uniform: waves 0..3
        const int off = (nfull * 512 + t) * 16;
        __builtin_amdgcn_global_load_lds((gl_u32*)(g + off), (lds_u32*)(l + off), 16, 0, 0);
    }
}

// ---------------- prep: f32 V -> f16x2-split tile images (once per launch) ----
__global__ __launch_bounds__(512) void prep_v(const float* __restrict__ V,
                                              VTile* __restrict__ W) {
    const int t   = threadIdx.x;
    const int it  = blockIdx.x;
    const int b   = blockIdx.y;
    const int c16 = t & 15;        // 16B column
    const int rg  = t >> 4;        // 0..31 -> rows rg*4+i of the 128-key tile
    const int ts  = rg >> 3;       // slot 0..3
    const int r0  = (rg & 7) * 4;  // row within slot
    VTile* w = W + (size_t)b * NIT + it;
    const f32x4* Vg = (const f32x4*)(V + ((size_t)b * SS + (size_t)it * (NS * TK) + rg * 4) * DD);
    half4_t hh[4];
#pragma unroll
    for (int i = 0; i < 4; ++i) {
        f32x4 v = Vg[i * 16 + c16];
        half4_t hi, lo;
#pragma unroll
        for (int j = 0; j < 4; ++j) {
            float x = v[j];
            h16 h = (h16)x;
            hi[j] = h;
            lo[j] = (h16)(x - (float)h);   // exact residual
        }
        hh[i] = hi;
        *(half4_t*)&w->Vhi[ts][(r0 + i) * SV + c16 * 4] = hi;
        *(half4_t*)&w->Vlo[ts][(r0 + i) * SV + c16 * 4] = lo;
    }
#pragma unroll
    for (int j = 0; j < 4; ++j) {
        half4_t col;
#pragma unroll
        for (int i = 0; i < 4; ++i) col[i] = hh[i][j];
        *(half4_t*)&w->VTr[ts][(c16 * 4 + j) * SVT + r0] = col;
    }
}

// S^T = V * Q^T on one 32-key slot, f16x2-split (err ~2^-20): 12 MFMA per call.
__device__ __forceinline__ void scores(const LdsBufs& L, int kq, int qi, int quad,
                                       const half8_t* qhi, const half8_t* qlo,
                                       f32x4* sc) {
    sc[0] = (f32x4){0.f, 0.f, 0.f, 0.f};
    sc[1] = (f32x4){0.f, 0.f, 0.f, 0.f};
#pragma unroll
    for (int ks = 0; ks < 2; ++ks) {
#pragma unroll
        for (int mt = 0; mt < 2; ++mt) {
            half8_t ahi = *(const half8_t*)&L.T.Vhi[kq][(mt * 16 + qi) * SV + ks * 32 + quad * 8];
            half8_t alo = *(const half8_t*)&L.T.Vlo[kq][(mt * 16 + qi) * SV + ks * 32 + quad * 8];
            sc[mt] = __builtin_amdgcn_mfma_f32_16x16x32_f16(ahi, qhi[ks], sc[mt], 0, 0, 0);
            sc[mt] = __builtin_amdgcn_mfma_f32_16x16x32_f16(ahi, qlo[ks], sc[mt], 0, 0, 0);
            sc[mt] = __builtin_amdgcn_mfma_f32_16x16x32_f16(alo, qhi[ks], sc[mt], 0, 0, 0);
        }
    }
}

__global__ __launch_bounds__(512, 4) void attn_fused(const float* __restrict__ Q,
                                                     const VTile* __restrict__ W,
                                                     float* __restrict__ ctx,
                                                     float* __restrict__ attn) {
    __shared__ LdsBufs L;
    const int t     = threadIdx.x;
    const int w     = t >> 6;
    const int lane  = t & 63;
    const int qi    = lane & 15;   // query (C col) / A-row index
    const int quad  = lane >> 4;   // 0..3
    const int qgrp  = w & 1;       // query group
    const int kq    = w >> 1;      // key quarter 0..3 (split-K=4)
    const int b     = blockIdx.y;
    const int qb    = blockIdx.x * QB + qgrp * 16;

    const VTile* Wb   = W + (size_t)b * NIT;
    const float* Qrow = Q + ((size_t)b * SS + qb + qi) * DD;

    // Q fragments, f16x2: lane holds Q[qi][ks*32 + quad*8 + j]
    half8_t qhi[2], qlo[2];
#pragma unroll
    for (int ks = 0; ks < 2; ++ks) {
        f32x4 a = *(const f32x4*)(Qrow + ks * 32 + quad * 8);
        f32x4 c = *(const f32x4*)(Qrow + ks * 32 + quad * 8 + 4);
#pragma unroll
        for (int j = 0; j < 4; ++j) {
            float x = a[j];
            h16 h = (h16)x;
            qhi[ks][j] = h;
            qlo[ks][j] = (h16)(x - (float)h);
            float y = c[j];
            h16 g = (h16)y;
            qhi[ks][j + 4] = g;
            qlo[ks][j + 4] = (h16)(y - (float)g);
        }
    }

    float mrun = -1e30f, lrun = 0.f;
    f32x4 oc[4];
#pragma unroll
    for (int mt = 0; mt < 4; ++mt) oc[mt] = (f32x4){0.f, 0.f, 0.f, 0.f};

    // ---------------- Phase 1: online softmax, ctx accumulate ----------------
    for (int it = 0; it < NIT; ++it) {
        __syncthreads();                                    // prev tile consumed
        stage_tile((const char*)(Wb + it), (char*)&L.T, t, 7, false);
        __syncthreads();                                    // vmcnt drained by compiler

        f32x4 sc[2];
        scores(L, kq, qi, quad, qhi, qlo, sc);

        float tmax = -1e30f;
#pragma unroll
        for (int mt = 0; mt < 2; ++mt)
#pragma unroll
            for (int r4 = 0; r4 < 4; ++r4) tmax = fmaxf(tmax, sc[mt][r4]);
        tmax = fmaxf(tmax, __shfl_xor(tmax, 16));
        tmax = fmaxf(tmax, __shfl_xor(tmax, 32));
        float mn    = fmaxf(mrun, tmax);
        float alpha = __expf(mrun - mn);
        float psum  = 0.f;
        half4_t pv[2];
#pragma unroll
        for (int mt = 0; mt < 2; ++mt)
#pragma unroll
            for (int r4 = 0; r4 < 4; ++r4) {
                float p = __expf(sc[mt][r4] - mn);
                psum += p;
                pv[mt][r4] = (h16)p;
            }
        psum += __shfl_xor(psum, 16);
        psum += __shfl_xor(psum, 32);
        lrun = lrun * alpha + psum;
        mrun = mn;
#pragma unroll
        for (int mt = 0; mt < 2; ++mt)
            *(half4_t*)&L.Pl[w][qi * SP + mt * 16 + quad * 4] = pv[mt];
#pragma unroll
        for (int mt = 0; mt < 4; ++mt) oc[mt] *= alpha;

        // O^T += V^T * P^T : A = VTr[d][key], B = Pl[q][key]; K = 32 keys
        half8_t bp = *(const half8_t*)&L.Pl[w][qi * SP + quad * 8];
#pragma unroll
        for (int mt = 0; mt < 4; ++mt) {
            half8_t av = *(const half8_t*)&L.T.VTr[kq][(mt * 16 + qi) * SVT + quad * 8];
            oc[mt] = __builtin_amdgcn_mfma_f32_16x16x32_f16(av, bp, oc[mt], 0, 0, 0);
        }
    }

    // ---------------- Merge 4 split-K partners (fixed order) ----------------
    __syncthreads();
    {
        float* buf  = (float*)&L;            // 512*18*4 = 36864 B scratch in T
        float* mine = buf + t * 18;
        mine[0] = mrun;
        mine[1] = lrun;
#pragma unroll
        for (int mt = 0; mt < 4; ++mt)
#pragma unroll
            for (int r4 = 0; r4 < 4; ++r4) mine[2 + mt * 4 + r4] = oc[mt][r4];
        __syncthreads();
        float mf = -1e30f;
#pragma unroll
        for (int k2 = 0; k2 < 4; ++k2)
            mf = fmaxf(mf, buf[((k2 * 2 + qgrp) * 64 + lane) * 18]);
        float lf = 0.f;
        f32x4 on[4];
#pragma unroll
        for (int mt = 0; mt < 4; ++mt) on[mt] = (f32x4){0.f, 0.f, 0.f, 0.f};
#pragma unroll
        for (int k2 = 0; k2 < 4; ++k2) {
            const float* po = buf + ((k2 * 2 + qgrp) * 64 + lane) * 18;
            float e = __expf(po[0] - mf);
            lf += po[1] * e;
#pragma unroll
            for (int mt = 0; mt < 4; ++mt)
#pragma unroll
                for (int r4 = 0; r4 < 4; ++r4) on[mt][r4] += po[2 + mt * 4 + r4] * e;
        }
        mrun = mf;
        lrun = lf;
#pragma unroll
        for (int mt = 0; mt < 4; ++mt) oc[mt] = on[mt];
    }

    const float invl = 1.f / lrun;

    // ctx write (key-quarter 0 waves): lane holds d = mt*16+quad*4+r for q = qi
    if (kq == 0) {
        float* crow = ctx + ((size_t)b * SS + qb + qi) * DD;
#pragma unroll
        for (int mt = 0; mt < 4; ++mt) {
            f32x4 cv;
#pragma unroll
            for (int r4 = 0; r4 < 4; ++r4) cv[r4] = oc[mt][r4] * invl;
            *(f32x4*)&crow[mt * 16 + quad * 4] = cv;
        }
    }

    // ---------------- Phase 2: recompute scores, write normalized weights ----
    const float moff = mrun + __logf(lrun);   // exp(s-m)/l == exp(s-moff)
    float* arow = attn + ((size_t)b * SS + qb + qi) * SS;
    for (int it = 0; it < NIT; ++it) {
        __syncthreads();
        stage_tile((const char*)(Wb + it), (char*)&L.T, t, 4, true);  // Vhi+Vlo only
        __syncthreads();

        f32x4 sc[2];
        scores(L, kq, qi, quad, qhi, qlo, sc);
        const int kbase = it * (NS * TK) + kq * TK;
#pragma unroll
        for (int mt = 0; mt < 2; ++mt) {
            f32x4 wv;
#pragma unroll
            for (int r4 = 0; r4 < 4; ++r4) wv[r4] = __expf(sc[mt][r4] - moff);
            // nontemporal: 268 MB of attn must not evict the L2-resident V image
            __builtin_nontemporal_store(wv, (f32x4*)&arow[kbase + mt * 16 + quad * 4]);
        }
    }
}

extern "C" void kernel_launch(void* const* d_in, const int* in_sizes, int n_in,
                              void* d_out, int out_size, void* d_ws, size_t ws_size,
                              hipStream_t stream) {
    const float* Q = (const float*)d_in[0];
    const float* V = (const float*)d_in[1];
    float* ctx  = (float*)d_out;
    float* attn = (float*)d_out + (size_t)BB * SS * DD;
    VTile* W = (VTile*)d_ws;   // needs BB*NIT*57344 = 7.0 MiB of workspace
    prep_v<<<dim3(NIT, BB), 512, 0, stream>>>(V, W);
    attn_fused<<<dim3(SS / QB, BB), 512, 0, stream>>>(Q, W, ctx, attn);
}